// Round 1
// baseline (555.672 us; speedup 1.0000x reference)
//
#include <hip/hip_runtime.h>
#include <cstdint>
#include <cstddef>

// ---------------------------------------------------------------------------
// TransformerLayer: hidden,k,v = f(x, qw,qb, kw,kb, vw,vb, w1,b1, w2,b2)
// S=4096, D_MODEL=2048, D_INT=512.  bf16 MFMA GEMMs, fp32 accumulate.
// ---------------------------------------------------------------------------

typedef __attribute__((ext_vector_type(8))) short short8;   // 8 x bf16 bits (4 VGPR)
typedef __attribute__((ext_vector_type(4))) float f32x4;    // MFMA accum

#define SEQ   4096
#define DMODEL 2048
#define DINT  512

// fp32 -> bf16 bits, round-to-nearest-even
__device__ __forceinline__ unsigned short f2bf(float f) {
  union { float f; unsigned int u; } a;
  a.f = f;
  unsigned int u = a.u;
  u += 0x7fffu + ((u >> 16) & 1u);
  return (unsigned short)(u >> 16);
}

// ---------------------------------------------------------------------------
// cast: fp32 -> bf16 (4 elems / thread)
// ---------------------------------------------------------------------------
__global__ __launch_bounds__(256) void cast_bf16_kernel(
    const float* __restrict__ in, unsigned short* __restrict__ out, int n4) {
  int i = blockIdx.x * 256 + threadIdx.x;
  if (i >= n4) return;
  float4 v = ((const float4*)in)[i];
  ushort4 o;
  o.x = f2bf(v.x); o.y = f2bf(v.y); o.z = f2bf(v.z); o.w = f2bf(v.w);
  ((ushort4*)out)[i] = o;
}

// ---------------------------------------------------------------------------
// GEMM: C[M,N] = scale * (A[M,K] @ B[N,K]^T)  (+bias) (+resid) (relu?)
//   A,B bf16 row-major; outputs: fp32, bf16, bf16-transposed ([N,M]) -- any
//   subset via non-null pointers.
// 128x128 block tile, 4 waves each owning 64x64 (4x4 frags of 16x16x32 MFMA),
// BK=32.  Reg-staged LDS with padded stride 56 (112B: 16B-aligned, fragment
// reads only 2-way bank-aliased per 16-lane quarter => ~free per m136).
// ---------------------------------------------------------------------------
#define BM 128
#define BN 128
#define BK 32
#define LDK 56   // padded LDS K-stride (elements)

__global__ __launch_bounds__(256)
void gemm_bt_kernel(const unsigned short* __restrict__ A,
                    const unsigned short* __restrict__ B,
                    int M, int N, int K,
                    const float* __restrict__ bias,    // [N] or null
                    const float* __restrict__ resid,   // [M,N] fp32 or null
                    float scale, int relu,
                    float* __restrict__ outF,          // [M,N] or null
                    unsigned short* __restrict__ outB, // [M,N] bf16 or null
                    unsigned short* __restrict__ outBT)// [N,M] bf16 or null
{
  __shared__ __align__(16) unsigned short As[BM][LDK];
  __shared__ __align__(16) unsigned short Bs[BN][LDK];

  const int tid  = threadIdx.x;
  const int lane = tid & 63;
  const int wave = tid >> 6;
  const int wr   = wave >> 1;        // wave row (0..1)
  const int wc   = wave & 1;         // wave col (0..1)
  const int brow = blockIdx.x * BM;
  const int bcol = blockIdx.y * BN;
  const int lr   = lane & 15;        // fragment row/col
  const int kg   = lane >> 4;        // k-group (0..3)

  // staging map: 256 threads, each stages one 16B chunk per 64-row half.
  // chunk c = tid: row = c>>2 (0..63), col8 = (c&3)*8
  const int sr0 = tid >> 2;
  const int sc0 = (tid & 3) * 8;

  f32x4 acc[4][4];
#pragma unroll
  for (int i = 0; i < 4; i++)
#pragma unroll
    for (int j = 0; j < 4; j++) acc[i][j] = (f32x4){0.f, 0.f, 0.f, 0.f};

  for (int k0 = 0; k0 < K; k0 += BK) {
    // global -> regs (coalesced 16B/lane)
    short8 av0 = *(const short8*)(A + (size_t)(brow + sr0)      * K + k0 + sc0);
    short8 av1 = *(const short8*)(A + (size_t)(brow + 64 + sr0) * K + k0 + sc0);
    short8 bv0 = *(const short8*)(B + (size_t)(bcol + sr0)      * K + k0 + sc0);
    short8 bv1 = *(const short8*)(B + (size_t)(bcol + 64 + sr0) * K + k0 + sc0);
    __syncthreads();                 // previous iter's frag reads done
    *(short8*)(&As[sr0][sc0])      = av0;
    *(short8*)(&As[64 + sr0][sc0]) = av1;
    *(short8*)(&Bs[sr0][sc0])      = bv0;
    *(short8*)(&Bs[64 + sr0][sc0]) = bv1;
    __syncthreads();                 // staged tile visible

    short8 aF[4], bF[4];
#pragma unroll
    for (int mi = 0; mi < 4; mi++)
      aF[mi] = *(const short8*)(&As[wr * 64 + mi * 16 + lr][kg * 8]);
#pragma unroll
    for (int ni = 0; ni < 4; ni++)
      bF[ni] = *(const short8*)(&Bs[wc * 64 + ni * 16 + lr][kg * 8]);

#pragma unroll
    for (int mi = 0; mi < 4; mi++)
#pragma unroll
      for (int ni = 0; ni < 4; ni++)
        acc[mi][ni] = __builtin_amdgcn_mfma_f32_16x16x32_bf16(
            aF[mi], bF[ni], acc[mi][ni], 0, 0, 0);
  }

  // epilogue: D row = (lane>>4)*4 + r, col = lane&15  [m89-verified mapping]
#pragma unroll
  for (int mi = 0; mi < 4; mi++) {
#pragma unroll
    for (int ni = 0; ni < 4; ni++) {
#pragma unroll
      for (int r = 0; r < 4; r++) {
        const int row = brow + wr * 64 + mi * 16 + kg * 4 + r;
        const int col = bcol + wc * 64 + ni * 16 + lr;
        float v = acc[mi][ni][r] * scale;
        if (bias)  v += bias[col];
        if (resid) v += resid[(size_t)row * N + col];
        if (relu)  v = fmaxf(v, 0.0f);
        if (outF)  outF[(size_t)row * N + col] = v;
        if (outB)  outB[(size_t)row * N + col] = f2bf(v);
        if (outBT) outBT[(size_t)col * M + row] = f2bf(v);
      }
    }
  }
}

// ---------------------------------------------------------------------------
// row softmax: one block per row of [SEQ, SEQ] fp32 scores -> bf16 probs
// ---------------------------------------------------------------------------
__global__ __launch_bounds__(256) void softmax_kernel(
    const float* __restrict__ Sc, unsigned short* __restrict__ P) {
  __shared__ float buf[SEQ];
  __shared__ float redm[4];
  __shared__ float reds[4];
  const int tid = threadIdx.x;
  const int row = blockIdx.x;
  const float* src = Sc + (size_t)row * SEQ;

  float lmax = -3.0e38f;
  for (int i = tid * 4; i < SEQ; i += 1024) {
    float4 v = *(const float4*)(src + i);
    buf[i] = v.x; buf[i + 1] = v.y; buf[i + 2] = v.z; buf[i + 3] = v.w;
    lmax = fmaxf(lmax, fmaxf(fmaxf(v.x, v.y), fmaxf(v.z, v.w)));
  }
#pragma unroll
  for (int off = 32; off > 0; off >>= 1)
    lmax = fmaxf(lmax, __shfl_xor(lmax, off, 64));
  if ((tid & 63) == 0) redm[tid >> 6] = lmax;
  __syncthreads();
  const float m = fmaxf(fmaxf(redm[0], redm[1]), fmaxf(redm[2], redm[3]));

  float lsum = 0.0f;
  for (int i = tid; i < SEQ; i += 256) {
    float e = __expf(buf[i] - m);
    buf[i] = e;
    lsum += e;
  }
#pragma unroll
  for (int off = 32; off > 0; off >>= 1)
    lsum += __shfl_xor(lsum, off, 64);
  if ((tid & 63) == 0) reds[tid >> 6] = lsum;
  __syncthreads();
  const float inv = 1.0f / (reds[0] + reds[1] + reds[2] + reds[3]);

  unsigned short* dst = P + (size_t)row * SEQ;
  for (int i = tid; i < SEQ; i += 256) dst[i] = f2bf(buf[i] * inv);
}

// ---------------------------------------------------------------------------
// launch
// ---------------------------------------------------------------------------
extern "C" void kernel_launch(void* const* d_in, const int* in_sizes, int n_in,
                              void* d_out, int out_size, void* d_ws, size_t ws_size,
                              hipStream_t stream) {
  const float* x  = (const float*)d_in[0];
  const float* qw = (const float*)d_in[1];
  const float* qb = (const float*)d_in[2];
  const float* kw = (const float*)d_in[3];
  const float* kb = (const float*)d_in[4];
  const float* vw = (const float*)d_in[5];
  const float* vb = (const float*)d_in[6];
  const float* w1 = (const float*)d_in[7];
  const float* b1 = (const float*)d_in[8];
  const float* w2 = (const float*)d_in[9];
  const float* b2 = (const float*)d_in[10];
  float* out = (float*)d_out;   // [hidden(8388608) | k(2097152) | v(8388608)]
  char* ws = (char*)d_ws;

  // workspace layout (bytes); Sc region is reused for XR/XRb/X1b after softmax
  unsigned short* Xb  = (unsigned short*)(ws + 0);          // 16 MiB  x bf16
  unsigned short* QWb = (unsigned short*)(ws + 16777216);   //  2 MiB
  unsigned short* KWb = (unsigned short*)(ws + 18874368);   //  2 MiB
  unsigned short* VWb = (unsigned short*)(ws + 20971520);   //  8 MiB
  unsigned short* W1b = (unsigned short*)(ws + 29360128);   //  8 MiB
  unsigned short* W2b = (unsigned short*)(ws + 37748736);   //  8 MiB
  unsigned short* Qb  = (unsigned short*)(ws + 46137344);   //  4 MiB  q bf16
  unsigned short* Kb  = (unsigned short*)(ws + 50331648);   //  4 MiB  k bf16
  unsigned short* VTb = (unsigned short*)(ws + 54525952);   // 16 MiB  v^T bf16
  float*          Sc  = (float*)(ws + 71303168);            // 64 MiB  scores fp32
  float*          XR  = (float*)(ws + 71303168);            // 32 MiB  x_residual (overlaps dead Sc)
  unsigned short* XRb = (unsigned short*)(ws + 104857600);  // 16 MiB  x_residual bf16
  unsigned short* X1b = (unsigned short*)(ws + 121634816);  // 16 MiB  relu(ff1) bf16
  unsigned short* Pb  = (unsigned short*)(ws + 138412032);  // 32 MiB  softmax probs bf16
  // total: 171,966,464 bytes (~164 MiB)

  // casts to bf16
  cast_bf16_kernel<<<8192, 256, 0, stream>>>(x,  Xb,  2097152);
  cast_bf16_kernel<<<1024, 256, 0, stream>>>(qw, QWb, 262144);
  cast_bf16_kernel<<<1024, 256, 0, stream>>>(kw, KWb, 262144);
  cast_bf16_kernel<<<4096, 256, 0, stream>>>(vw, VWb, 1048576);
  cast_bf16_kernel<<<4096, 256, 0, stream>>>(w1, W1b, 1048576);
  cast_bf16_kernel<<<4096, 256, 0, stream>>>(w2, W2b, 1048576);

  const dim3 blk(256);
  // q = x @ qw^T + qb                      -> bf16
  gemm_bt_kernel<<<dim3(32, 4), blk, 0, stream>>>(
      Xb, QWb, SEQ, DINT, DMODEL, qb, nullptr, 1.0f, 0, nullptr, Qb, nullptr);
  // k = x @ kw^T + kb                      -> fp32 (out) + bf16
  gemm_bt_kernel<<<dim3(32, 4), blk, 0, stream>>>(
      Xb, KWb, SEQ, DINT, DMODEL, kb, nullptr, 1.0f, 0, out + 8388608, Kb, nullptr);
  // v = x @ vw^T + vb                      -> fp32 (out) + bf16 transposed
  gemm_bt_kernel<<<dim3(32, 16), blk, 0, stream>>>(
      Xb, VWb, SEQ, DMODEL, DMODEL, vb, nullptr, 1.0f, 0, out + 10485760, nullptr, VTb);
  // scores = (q @ k^T) / sqrt(512)         -> fp32
  gemm_bt_kernel<<<dim3(32, 32), blk, 0, stream>>>(
      Qb, Kb, SEQ, SEQ, DINT, nullptr, nullptr, 0.04419417382415922f, 0,
      Sc, nullptr, nullptr);
  // P = softmax(scores)                    -> bf16
  softmax_kernel<<<4096, blk, 0, stream>>>(Sc, Pb);
  // x_residual = P @ V + x                 -> fp32 + bf16   (V^T is B-layout)
  gemm_bt_kernel<<<dim3(32, 16), blk, 0, stream>>>(
      Pb, VTb, SEQ, DMODEL, SEQ, nullptr, x, 1.0f, 0, XR, XRb, nullptr);
  // x1 = relu(x_residual @ w1^T + b1)      -> bf16
  gemm_bt_kernel<<<dim3(32, 16), blk, 0, stream>>>(
      XRb, W1b, SEQ, DMODEL, DMODEL, b1, nullptr, 1.0f, 1, nullptr, X1b, nullptr);
  // hidden = x1 @ w2^T + b2 + x_residual   -> fp32 (out)
  gemm_bt_kernel<<<dim3(32, 16), blk, 0, stream>>>(
      X1b, W2b, SEQ, DMODEL, DMODEL, b2, XR, 1.0f, 0, out, nullptr, nullptr);
}

// Round 2
// 547.982 us; speedup vs baseline: 1.0140x; 1.0140x over previous
//
#include <hip/hip_runtime.h>
#include <cstdint>
#include <cstddef>

// ---------------------------------------------------------------------------
// TransformerLayer: hidden,k,v = f(x, qw,qb, kw,kb, vw,vb, w1,b1, w2,b2)
// S=4096, D_MODEL=2048, D_INT=512.  bf16 MFMA GEMMs, fp32 accumulate.
// Round 2: m97 structure — global_load_lds(16B) staging, linear LDS, BK=32.
// ---------------------------------------------------------------------------

typedef __attribute__((ext_vector_type(8))) short short8;   // 8 x bf16 bits (4 VGPR)
typedef __attribute__((ext_vector_type(4))) float f32x4;    // MFMA accum

#define SEQ   4096
#define DMODEL 2048
#define DINT  512

// fp32 -> bf16 bits, round-to-nearest-even
__device__ __forceinline__ unsigned short f2bf(float f) {
  union { float f; unsigned int u; } a;
  a.f = f;
  unsigned int u = a.u;
  u += 0x7fffu + ((u >> 16) & 1u);
  return (unsigned short)(u >> 16);
}

// ---------------------------------------------------------------------------
// cast: fp32 -> bf16 (4 elems / thread)
// ---------------------------------------------------------------------------
__global__ __launch_bounds__(256) void cast_bf16_kernel(
    const float* __restrict__ in, unsigned short* __restrict__ out, int n4) {
  int i = blockIdx.x * 256 + threadIdx.x;
  if (i >= n4) return;
  float4 v = ((const float4*)in)[i];
  ushort4 o;
  o.x = f2bf(v.x); o.y = f2bf(v.y); o.z = f2bf(v.z); o.w = f2bf(v.w);
  ((ushort4*)out)[i] = o;
}

// ---------------------------------------------------------------------------
// GEMM: C[M,N] = scale * (A[M,K] @ B[N,K]^T)  (+bias) (+resid) (relu?)
//   A,B bf16 row-major; outputs: fp32, bf16, bf16-transposed ([N,M]) -- any
//   subset via non-null pointers.
// m97 structure: 128x128 tile, BK=32, LINEAR LDS (required by global_load_lds:
// dest = wave-uniform base + lane*16B), 4 waves x (4x4 of 16x16x32 MFMA).
// Per K-step per wave: 4 global_load_lds_dwordx4 + 8 ds_read_b128 + 16 MFMA.
// ---------------------------------------------------------------------------
#define BM 128
#define BN 128
#define BK 32

__global__ __launch_bounds__(256)
void gemm_bt_kernel(const unsigned short* __restrict__ A,
                    const unsigned short* __restrict__ B,
                    int M, int N, int K,
                    const float* __restrict__ bias,    // [N] or null
                    const float* __restrict__ resid,   // [M,N] fp32 or null
                    float scale, int relu,
                    float* __restrict__ outF,          // [M,N] or null
                    unsigned short* __restrict__ outB, // [M,N] bf16 or null
                    unsigned short* __restrict__ outBT)// [N,M] bf16 or null
{
  __shared__ __align__(16) unsigned short As[BM][BK];   // 8 KiB, linear
  __shared__ __align__(16) unsigned short Bs[BN][BK];   // 8 KiB, linear

  const int tid  = threadIdx.x;
  const int lane = tid & 63;
  const int wave = tid >> 6;
  const int wr   = wave >> 1;        // wave row (0..1)
  const int wc   = wave & 1;         // wave col (0..1)
  const int brow = blockIdx.x * BM;
  const int bcol = blockIdx.y * BN;
  const int lr   = lane & 15;        // fragment row/col
  const int kg   = lane >> 4;        // k-group (0..3)

  // staging: one row of the K-tile = 32 bf16 = 64 B = 4 lanes x 16 B.
  // One global_load_lds (64 lanes x 16 B = 1 KiB) covers 16 rows.
  // Wave w stages rows [32w, 32w+32) of A and of B (2 chunks each).
  // Lane l within a chunk: row = rowbase + (l>>2), col = (l&3)*8.
  const size_t aOff = (size_t)(brow + wave * 32 + (lane >> 2)) * K + (lane & 3) * 8;
  const size_t bOff = (size_t)(bcol + wave * 32 + (lane >> 2)) * K + (lane & 3) * 8;
  const size_t rowSkip = (size_t)16 * K;   // +16 rows for second chunk

  f32x4 acc[4][4];
#pragma unroll
  for (int i = 0; i < 4; i++)
#pragma unroll
    for (int j = 0; j < 4; j++) acc[i][j] = (f32x4){0.f, 0.f, 0.f, 0.f};

  typedef __attribute__((address_space(3))) void lds_void;
  typedef __attribute__((address_space(1))) void g_void;

  for (int k0 = 0; k0 < K; k0 += BK) {
    __syncthreads();                 // previous iter's frag reads done
    __builtin_amdgcn_global_load_lds((const g_void*)(A + aOff + k0),
                                     (lds_void*)&As[wave * 32][0],      16, 0, 0);
    __builtin_amdgcn_global_load_lds((const g_void*)(A + aOff + rowSkip + k0),
                                     (lds_void*)&As[wave * 32 + 16][0], 16, 0, 0);
    __builtin_amdgcn_global_load_lds((const g_void*)(B + bOff + k0),
                                     (lds_void*)&Bs[wave * 32][0],      16, 0, 0);
    __builtin_amdgcn_global_load_lds((const g_void*)(B + bOff + rowSkip + k0),
                                     (lds_void*)&Bs[wave * 32 + 16][0], 16, 0, 0);
    __syncthreads();                 // staged tile visible (vmcnt drain @ barrier)

    short8 aF[4], bF[4];
#pragma unroll
    for (int mi = 0; mi < 4; mi++)
      aF[mi] = *(const short8*)(&As[wr * 64 + mi * 16 + lr][kg * 8]);
#pragma unroll
    for (int ni = 0; ni < 4; ni++)
      bF[ni] = *(const short8*)(&Bs[wc * 64 + ni * 16 + lr][kg * 8]);

#pragma unroll
    for (int mi = 0; mi < 4; mi++)
#pragma unroll
      for (int ni = 0; ni < 4; ni++)
        acc[mi][ni] = __builtin_amdgcn_mfma_f32_16x16x32_bf16(
            aF[mi], bF[ni], acc[mi][ni], 0, 0, 0);
  }

  // epilogue: D row = (lane>>4)*4 + r, col = lane&15  [m89-verified mapping]
#pragma unroll
  for (int mi = 0; mi < 4; mi++) {
#pragma unroll
    for (int ni = 0; ni < 4; ni++) {
#pragma unroll
      for (int r = 0; r < 4; r++) {
        const int row = brow + wr * 64 + mi * 16 + kg * 4 + r;
        const int col = bcol + wc * 64 + ni * 16 + lr;
        float v = acc[mi][ni][r] * scale;
        if (bias)  v += bias[col];
        if (resid) v += resid[(size_t)row * N + col];
        if (relu)  v = fmaxf(v, 0.0f);
        if (outF)  outF[(size_t)row * N + col] = v;
        if (outB)  outB[(size_t)row * N + col] = f2bf(v);
        if (outBT) outBT[(size_t)col * M + row] = f2bf(v);
      }
    }
  }
}

// ---------------------------------------------------------------------------
// row softmax: one block per row of [SEQ, SEQ] fp32 scores -> bf16 probs
// ---------------------------------------------------------------------------
__global__ __launch_bounds__(256) void softmax_kernel(
    const float* __restrict__ Sc, unsigned short* __restrict__ P) {
  __shared__ float buf[SEQ];
  __shared__ float redm[4];
  __shared__ float reds[4];
  const int tid = threadIdx.x;
  const int row = blockIdx.x;
  const float* src = Sc + (size_t)row * SEQ;

  float lmax = -3.0e38f;
  for (int i = tid * 4; i < SEQ; i += 1024) {
    float4 v = *(const float4*)(src + i);
    buf[i] = v.x; buf[i + 1] = v.y; buf[i + 2] = v.z; buf[i + 3] = v.w;
    lmax = fmaxf(lmax, fmaxf(fmaxf(v.x, v.y), fmaxf(v.z, v.w)));
  }
#pragma unroll
  for (int off = 32; off > 0; off >>= 1)
    lmax = fmaxf(lmax, __shfl_xor(lmax, off, 64));
  if ((tid & 63) == 0) redm[tid >> 6] = lmax;
  __syncthreads();
  const float m = fmaxf(fmaxf(redm[0], redm[1]), fmaxf(redm[2], redm[3]));

  float lsum = 0.0f;
  for (int i = tid; i < SEQ; i += 256) {
    float e = __expf(buf[i] - m);
    buf[i] = e;
    lsum += e;
  }
#pragma unroll
  for (int off = 32; off > 0; off >>= 1)
    lsum += __shfl_xor(lsum, off, 64);
  if ((tid & 63) == 0) reds[tid >> 6] = lsum;
  __syncthreads();
  const float inv = 1.0f / (reds[0] + reds[1] + reds[2] + reds[3]);

  unsigned short* dst = P + (size_t)row * SEQ;
  for (int i = tid; i < SEQ; i += 256) dst[i] = f2bf(buf[i] * inv);
}

// ---------------------------------------------------------------------------
// launch
// ---------------------------------------------------------------------------
extern "C" void kernel_launch(void* const* d_in, const int* in_sizes, int n_in,
                              void* d_out, int out_size, void* d_ws, size_t ws_size,
                              hipStream_t stream) {
  const float* x  = (const float*)d_in[0];
  const float* qw = (const float*)d_in[1];
  const float* qb = (const float*)d_in[2];
  const float* kw = (const float*)d_in[3];
  const float* kb = (const float*)d_in[4];
  const float* vw = (const float*)d_in[5];
  const float* vb = (const float*)d_in[6];
  const float* w1 = (const float*)d_in[7];
  const float* b1 = (const float*)d_in[8];
  const float* w2 = (const float*)d_in[9];
  const float* b2 = (const float*)d_in[10];
  float* out = (float*)d_out;   // [hidden(8388608) | k(2097152) | v(8388608)]
  char* ws = (char*)d_ws;

  // workspace layout (bytes); Sc region is reused for XR after softmax
  unsigned short* Xb  = (unsigned short*)(ws + 0);          // 16 MiB  x bf16
  unsigned short* QWb = (unsigned short*)(ws + 16777216);   //  2 MiB
  unsigned short* KWb = (unsigned short*)(ws + 18874368);   //  2 MiB
  unsigned short* VWb = (unsigned short*)(ws + 20971520);   //  8 MiB
  unsigned short* W1b = (unsigned short*)(ws + 29360128);   //  8 MiB
  unsigned short* W2b = (unsigned short*)(ws + 37748736);   //  8 MiB
  unsigned short* Qb  = (unsigned short*)(ws + 46137344);   //  4 MiB  q bf16
  unsigned short* Kb  = (unsigned short*)(ws + 50331648);   //  4 MiB  k bf16
  unsigned short* VTb = (unsigned short*)(ws + 54525952);   // 16 MiB  v^T bf16
  float*          Sc  = (float*)(ws + 71303168);            // 64 MiB  scores fp32
  float*          XR  = (float*)(ws + 71303168);            // 32 MiB  x_residual (overlaps dead Sc)
  unsigned short* XRb = (unsigned short*)(ws + 104857600);  // 16 MiB  x_residual bf16
  unsigned short* X1b = (unsigned short*)(ws + 121634816);  // 16 MiB  relu(ff1) bf16
  unsigned short* Pb  = (unsigned short*)(ws + 138412032);  // 32 MiB  softmax probs bf16
  // total: 171,966,464 bytes (~164 MiB)

  // casts to bf16
  cast_bf16_kernel<<<8192, 256, 0, stream>>>(x,  Xb,  2097152);
  cast_bf16_kernel<<<1024, 256, 0, stream>>>(qw, QWb, 262144);
  cast_bf16_kernel<<<1024, 256, 0, stream>>>(kw, KWb, 262144);
  cast_bf16_kernel<<<4096, 256, 0, stream>>>(vw, VWb, 1048576);
  cast_bf16_kernel<<<4096, 256, 0, stream>>>(w1, W1b, 1048576);
  cast_bf16_kernel<<<4096, 256, 0, stream>>>(w2, W2b, 1048576);

  const dim3 blk(256);
  // q = x @ qw^T + qb                      -> bf16
  gemm_bt_kernel<<<dim3(32, 4), blk, 0, stream>>>(
      Xb, QWb, SEQ, DINT, DMODEL, qb, nullptr, 1.0f, 0, nullptr, Qb, nullptr);
  // k = x @ kw^T + kb                      -> fp32 (out) + bf16
  gemm_bt_kernel<<<dim3(32, 4), blk, 0, stream>>>(
      Xb, KWb, SEQ, DINT, DMODEL, kb, nullptr, 1.0f, 0, out + 8388608, Kb, nullptr);
  // v = x @ vw^T + vb                      -> fp32 (out) + bf16 transposed
  gemm_bt_kernel<<<dim3(32, 16), blk, 0, stream>>>(
      Xb, VWb, SEQ, DMODEL, DMODEL, vb, nullptr, 1.0f, 0, out + 10485760, nullptr, VTb);
  // scores = (q @ k^T) / sqrt(512)         -> fp32
  gemm_bt_kernel<<<dim3(32, 32), blk, 0, stream>>>(
      Qb, Kb, SEQ, SEQ, DINT, nullptr, nullptr, 0.04419417382415922f, 0,
      Sc, nullptr, nullptr);
  // P = softmax(scores)                    -> bf16
  softmax_kernel<<<4096, blk, 0, stream>>>(Sc, Pb);
  // x_residual = P @ V + x                 -> fp32 + bf16   (V^T is B-layout)
  gemm_bt_kernel<<<dim3(32, 16), blk, 0, stream>>>(
      Pb, VTb, SEQ, DMODEL, SEQ, nullptr, x, 1.0f, 0, XR, XRb, nullptr);
  // x1 = relu(x_residual @ w1^T + b1)      -> bf16
  gemm_bt_kernel<<<dim3(32, 16), blk, 0, stream>>>(
      XRb, W1b, SEQ, DMODEL, DMODEL, b1, nullptr, 1.0f, 1, nullptr, X1b, nullptr);
  // hidden = x1 @ w2^T + b2 + x_residual   -> fp32 (out)
  gemm_bt_kernel<<<dim3(32, 16), blk, 0, stream>>>(
      X1b, W2b, SEQ, DMODEL, DMODEL, b2, XR, 1.0f, 0, out, nullptr, nullptr);
}

// Round 3
// 490.175 us; speedup vs baseline: 1.1336x; 1.1179x over previous
//
#include <hip/hip_runtime.h>
#include <cstdint>
#include <cstddef>

// ---------------------------------------------------------------------------
// TransformerLayer: hidden,k,v = f(x, qw,qb, kw,kb, vw,vb, w1,b1, w2,b2)
// S=4096, D_MODEL=2048, D_INT=512.  bf16 MFMA GEMMs, fp32 accumulate.
// Round 3: 2-phase double-buffered GEMM (T3-minimum), BK=64, prefetch-then-
// compute, 1 barrier per K-tile.  Q+K fused (split epilogue).  Coalesced V
// write + separate LDS transpose kernel.
// ---------------------------------------------------------------------------

typedef __attribute__((ext_vector_type(8))) short short8;   // 8 x bf16 bits
typedef __attribute__((ext_vector_type(4))) float f32x4;    // MFMA accum

#define SEQ    4096
#define DMODEL 2048
#define DINT   512

// fp32 -> bf16 bits, round-to-nearest-even
__device__ __forceinline__ unsigned short f2bf(float f) {
  union { float f; unsigned int u; } a;
  a.f = f;
  unsigned int u = a.u;
  u += 0x7fffu + ((u >> 16) & 1u);
  return (unsigned short)(u >> 16);
}

// ---------------------------------------------------------------------------
// cast: fp32 -> bf16 (4 elems / thread)
// ---------------------------------------------------------------------------
__global__ __launch_bounds__(256) void cast_bf16_kernel(
    const float* __restrict__ in, unsigned short* __restrict__ out, int n4) {
  int i = blockIdx.x * 256 + threadIdx.x;
  if (i >= n4) return;
  float4 v = ((const float4*)in)[i];
  ushort4 o;
  o.x = f2bf(v.x); o.y = f2bf(v.y); o.z = f2bf(v.z); o.w = f2bf(v.w);
  ((ushort4*)out)[i] = o;
}

// ---------------------------------------------------------------------------
// bf16 transpose: out[C][R] = in[R][C].  64x64 LDS tile, padded, coalesced
// 128B on both sides.
// ---------------------------------------------------------------------------
__global__ __launch_bounds__(256) void transpose_bf16_kernel(
    const unsigned short* __restrict__ in, unsigned short* __restrict__ out,
    int R, int C) {
  __shared__ unsigned short tile[64][65];
  const int tx = threadIdx.x & 63;
  const int ty = threadIdx.x >> 6;          // 0..3
  const int r0 = blockIdx.x * 64;
  const int c0 = blockIdx.y * 64;
#pragma unroll
  for (int i = 0; i < 64; i += 4)
    tile[ty + i][tx] = in[(size_t)(r0 + ty + i) * C + c0 + tx];
  __syncthreads();
#pragma unroll
  for (int i = 0; i < 64; i += 4)
    out[(size_t)(c0 + ty + i) * R + r0 + tx] = tile[tx][ty + i];
}

// ---------------------------------------------------------------------------
// GEMM: C[M,N] = scale * (A[M,K] @ B[N,K]^T)  (+bias) (+resid) (relu?)
// 2-phase double-buffered: 128x128 tile, BK=64, 4 waves x (4x4 frags 16x16x32).
// Prefetch tile t+1 via global_load_lds(16B) into buf^1 BEFORE computing tile
// t; single __syncthreads per K-tile (compiler emits vmcnt(0)+lgkmcnt(0)
// drain there -- loads have ~32 MFMA of cover).
// Split epilogue: cols [0,split) -> {biasA, outFA, outBA} with row stride
// split; cols [split,N) -> {biasB, outFB, outBB} with row stride N-split.
// resid (fp32 [M,N]) applies to the A-side only (used with split==N).
// ---------------------------------------------------------------------------
#define BM 128
#define BN 128
#define BK 64

__global__ __launch_bounds__(256)
void gemm_bt_kernel(const unsigned short* __restrict__ A,
                    const unsigned short* __restrict__ B,
                    int M, int N, int K, int split,
                    const float* __restrict__ biasA,
                    const float* __restrict__ biasB,
                    const float* __restrict__ resid,
                    float scale, int relu,
                    float* __restrict__ outFA,
                    unsigned short* __restrict__ outBA,
                    float* __restrict__ outFB,
                    unsigned short* __restrict__ outBB)
{
  __shared__ __align__(16) unsigned short As[2][BM][BK];   // 2 x 16 KiB
  __shared__ __align__(16) unsigned short Bs[2][BN][BK];   // 2 x 16 KiB

  const int tid  = threadIdx.x;
  const int lane = tid & 63;
  const int wave = tid >> 6;
  const int wr   = wave >> 1;        // wave row (0..1)
  const int wc   = wave & 1;         // wave col (0..1)
  const int brow = blockIdx.x * BM;
  const int bcol = blockIdx.y * BN;
  const int lr   = lane & 15;        // fragment row/col
  const int kg   = lane >> 4;        // k-group (0..3)

  // staging: K-tile row = 64 bf16 = 128B = 8 lanes x 16B.
  // One block-wide call (256 thr x 16B = 4KB) covers 32 rows; 4 calls per
  // operand per tile.  LDS dest must be wave-uniform base + lane*16B.
  const int srow  = tid >> 3;          // 0..31 (row within call)
  const int scol  = (tid & 7) * 8;     // elem col within row
  const int wbase = wave * 8;          // wave-uniform LDS row base within call
  const unsigned short* Ab = A + (size_t)(brow + srow) * K + scol;
  const unsigned short* Bb = B + (size_t)(bcol + srow) * K + scol;

  typedef __attribute__((address_space(3))) void lds_void;
  typedef __attribute__((address_space(1))) void g_void;

  f32x4 acc[4][4];
#pragma unroll
  for (int i = 0; i < 4; i++)
#pragma unroll
    for (int j = 0; j < 4; j++) acc[i][j] = (f32x4){0.f, 0.f, 0.f, 0.f};

  auto stage = [&](int d, int k0) {
#pragma unroll
    for (int j = 0; j < 4; ++j) {
      __builtin_amdgcn_global_load_lds((const g_void*)(Ab + (size_t)(j * 32) * K + k0),
                                       (lds_void*)&As[d][j * 32 + wbase][0], 16, 0, 0);
      __builtin_amdgcn_global_load_lds((const g_void*)(Bb + (size_t)(j * 32) * K + k0),
                                       (lds_void*)&Bs[d][j * 32 + wbase][0], 16, 0, 0);
    }
  };

  auto compute = [&](int d) {
    short8 aF[4][2], bF[4][2];
#pragma unroll
    for (int mi = 0; mi < 4; ++mi)
#pragma unroll
      for (int ks = 0; ks < 2; ++ks)
        aF[mi][ks] = *(const short8*)&As[d][wr * 64 + mi * 16 + lr][ks * 32 + kg * 8];
#pragma unroll
    for (int ni = 0; ni < 4; ++ni)
#pragma unroll
      for (int ks = 0; ks < 2; ++ks)
        bF[ni][ks] = *(const short8*)&Bs[d][wc * 64 + ni * 16 + lr][ks * 32 + kg * 8];
#pragma unroll
    for (int ks = 0; ks < 2; ++ks)
#pragma unroll
      for (int mi = 0; mi < 4; ++mi)
#pragma unroll
        for (int ni = 0; ni < 4; ++ni)
          acc[mi][ni] = __builtin_amdgcn_mfma_f32_16x16x32_bf16(
              aF[mi][ks], bF[ni][ks], acc[mi][ni], 0, 0, 0);
  };

  // prologue
  stage(0, 0);
  __syncthreads();                       // vmcnt(0) drain: tile 0 resident
  int c = 0;
  const int NT = K >> 6;
  for (int t = 0; t < NT; ++t) {
    if (t + 1 < NT) stage(c ^ 1, (t + 1) << 6);  // prefetch next (other buf)
    compute(c);                                   // MFMA covers load latency
    __syncthreads();                              // drain vmcnt + lgkm; swap
    c ^= 1;
  }

  // epilogue: D row = (lane>>4)*4 + r, col = lane&15  [m89-verified mapping]
  const int wB = N - split;
#pragma unroll
  for (int mi = 0; mi < 4; mi++) {
#pragma unroll
    for (int ni = 0; ni < 4; ni++) {
#pragma unroll
      for (int r = 0; r < 4; r++) {
        const int row = brow + wr * 64 + mi * 16 + kg * 4 + r;
        const int col = bcol + wc * 64 + ni * 16 + lr;
        float v = acc[mi][ni][r] * scale;
        if (col < split) {
          if (biasA) v += biasA[col];
          if (resid) v += resid[(size_t)row * N + col];
          if (relu)  v = fmaxf(v, 0.0f);
          if (outFA) outFA[(size_t)row * split + col] = v;
          if (outBA) outBA[(size_t)row * split + col] = f2bf(v);
        } else {
          const int c2 = col - split;
          if (biasB) v += biasB[c2];
          if (outFB) outFB[(size_t)row * wB + c2] = v;
          if (outBB) outBB[(size_t)row * wB + c2] = f2bf(v);
        }
      }
    }
  }
}

// ---------------------------------------------------------------------------
// row softmax: one block per row of [SEQ, SEQ] fp32 scores -> bf16 probs
// ---------------------------------------------------------------------------
__global__ __launch_bounds__(256) void softmax_kernel(
    const float* __restrict__ Sc, unsigned short* __restrict__ P) {
  __shared__ float buf[SEQ];
  __shared__ float redm[4];
  __shared__ float reds[4];
  const int tid = threadIdx.x;
  const int row = blockIdx.x;
  const float* src = Sc + (size_t)row * SEQ;

  float lmax = -3.0e38f;
  for (int i = tid * 4; i < SEQ; i += 1024) {
    float4 v = *(const float4*)(src + i);
    buf[i] = v.x; buf[i + 1] = v.y; buf[i + 2] = v.z; buf[i + 3] = v.w;
    lmax = fmaxf(lmax, fmaxf(fmaxf(v.x, v.y), fmaxf(v.z, v.w)));
  }
#pragma unroll
  for (int off = 32; off > 0; off >>= 1)
    lmax = fmaxf(lmax, __shfl_xor(lmax, off, 64));
  if ((tid & 63) == 0) redm[tid >> 6] = lmax;
  __syncthreads();
  const float m = fmaxf(fmaxf(redm[0], redm[1]), fmaxf(redm[2], redm[3]));

  float lsum = 0.0f;
  for (int i = tid; i < SEQ; i += 256) {
    float e = __expf(buf[i] - m);
    buf[i] = e;
    lsum += e;
  }
#pragma unroll
  for (int off = 32; off > 0; off >>= 1)
    lsum += __shfl_xor(lsum, off, 64);
  if ((tid & 63) == 0) reds[tid >> 6] = lsum;
  __syncthreads();
  const float inv = 1.0f / (reds[0] + reds[1] + reds[2] + reds[3]);

  unsigned short* dst = P + (size_t)row * SEQ;
  for (int i = tid; i < SEQ; i += 256) dst[i] = f2bf(buf[i] * inv);
}

// ---------------------------------------------------------------------------
// launch
// ---------------------------------------------------------------------------
extern "C" void kernel_launch(void* const* d_in, const int* in_sizes, int n_in,
                              void* d_out, int out_size, void* d_ws, size_t ws_size,
                              hipStream_t stream) {
  const float* x  = (const float*)d_in[0];
  const float* qw = (const float*)d_in[1];
  const float* qb = (const float*)d_in[2];
  const float* kw = (const float*)d_in[3];
  const float* kb = (const float*)d_in[4];
  const float* vw = (const float*)d_in[5];
  const float* vb = (const float*)d_in[6];
  const float* w1 = (const float*)d_in[7];
  const float* b1 = (const float*)d_in[8];
  const float* w2 = (const float*)d_in[9];
  const float* b2 = (const float*)d_in[10];
  float* out = (float*)d_out;   // [hidden(8388608) | k(2097152) | v(8388608)]
  char* ws = (char*)d_ws;

  // workspace layout (1 MiB = 1048576 B), aggressive overlap:
  //   [0,28M):   Xb(16M) + VWb(8M) + QKWb(4M)   -- all dead after V-GEMM
  //              Pb(32M) overlays [0,32M) from softmax on
  //   [32,48M):  W1b, W2b
  //   [48,56M):  Qb, Kb                         -- dead after S-GEMM
  //   [56,72M):  Vb                             -- dead after transpose
  //   [72,88M):  VTb
  //   [88,152M): Sc(64M fp32)                   -- dead after softmax
  //              XR(32M)@88M, X1b(16M)@120M, XRb(16M)@136M overlay it
  const size_t MB = 1048576;
  unsigned short* Xb   = (unsigned short*)(ws + 0 * MB);
  unsigned short* VWb  = (unsigned short*)(ws + 16 * MB);
  unsigned short* QKWb = (unsigned short*)(ws + 24 * MB);
  unsigned short* Pb   = (unsigned short*)(ws + 0 * MB);     // overlays Xb/VWb/QKWb
  unsigned short* W1b  = (unsigned short*)(ws + 32 * MB);
  unsigned short* W2b  = (unsigned short*)(ws + 40 * MB);
  unsigned short* Qb   = (unsigned short*)(ws + 48 * MB);
  unsigned short* Kb   = (unsigned short*)(ws + 52 * MB);
  unsigned short* Vb   = (unsigned short*)(ws + 56 * MB);
  unsigned short* VTb  = (unsigned short*)(ws + 72 * MB);
  float*          Sc   = (float*)(ws + 88 * MB);
  float*          XR   = (float*)(ws + 88 * MB);             // overlays dead Sc
  unsigned short* X1b  = (unsigned short*)(ws + 120 * MB);   // overlays dead Sc
  unsigned short* XRb  = (unsigned short*)(ws + 136 * MB);   // overlays dead Sc
  // total footprint: 152 MiB

  // casts to bf16 (QKWb = [qw ; kw] rows concatenated)
  cast_bf16_kernel<<<8192, 256, 0, stream>>>(x,  Xb,  2097152);
  cast_bf16_kernel<<<1024, 256, 0, stream>>>(qw, QKWb, 262144);
  cast_bf16_kernel<<<1024, 256, 0, stream>>>(kw, QKWb + 512 * 2048, 262144);
  cast_bf16_kernel<<<4096, 256, 0, stream>>>(vw, VWb, 1048576);
  cast_bf16_kernel<<<4096, 256, 0, stream>>>(w1, W1b, 1048576);
  cast_bf16_kernel<<<4096, 256, 0, stream>>>(w2, W2b, 1048576);

  const dim3 blk(256);
  // q,k = x @ [qw;kw]^T + [qb;kb]   (fused, split epilogue)
  //   cols <512: q -> Qb bf16; cols >=512: k -> out fp32 + Kb bf16
  gemm_bt_kernel<<<dim3(32, 8), blk, 0, stream>>>(
      Xb, QKWb, SEQ, 1024, DMODEL, 512, qb, kb, nullptr, 1.0f, 0,
      nullptr, Qb, out + 8388608, Kb);
  // v = x @ vw^T + vb   -> fp32 (out) + bf16 (coalesced)
  gemm_bt_kernel<<<dim3(32, 16), blk, 0, stream>>>(
      Xb, VWb, SEQ, DMODEL, DMODEL, DMODEL, vb, nullptr, nullptr, 1.0f, 0,
      out + 10485760, Vb, nullptr, nullptr);
  // VTb = Vb^T  ([2048][4096])
  transpose_bf16_kernel<<<dim3(64, 32), blk, 0, stream>>>(Vb, VTb, SEQ, DMODEL);
  // scores = (q @ k^T) / sqrt(512)  -> fp32
  gemm_bt_kernel<<<dim3(32, 32), blk, 0, stream>>>(
      Qb, Kb, SEQ, SEQ, DINT, SEQ, nullptr, nullptr, nullptr,
      0.04419417382415922f, 0, Sc, nullptr, nullptr, nullptr);
  // P = softmax(scores)  -> bf16
  softmax_kernel<<<4096, blk, 0, stream>>>(Sc, Pb);
  // x_residual = P @ V + x  -> fp32 + bf16   (VTb is B-layout [N,K])
  gemm_bt_kernel<<<dim3(32, 16), blk, 0, stream>>>(
      Pb, VTb, SEQ, DMODEL, SEQ, DMODEL, nullptr, nullptr, x, 1.0f, 0,
      XR, XRb, nullptr, nullptr);
  // x1 = relu(x_residual @ w1^T + b1)  -> bf16
  gemm_bt_kernel<<<dim3(32, 16), blk, 0, stream>>>(
      XRb, W1b, SEQ, DMODEL, DMODEL, DMODEL, b1, nullptr, nullptr, 1.0f, 1,
      nullptr, X1b, nullptr, nullptr);
  // hidden = x1 @ w2^T + b2 + x_residual  -> fp32 (out)
  gemm_bt_kernel<<<dim3(32, 16), blk, 0, stream>>>(
      X1b, W2b, SEQ, DMODEL, DMODEL, DMODEL, b2, nullptr, XR, 1.0f, 0,
      out, nullptr, nullptr, nullptr);
}